// Round 8
// baseline (312.226 us; speedup 1.0000x reference)
//
#include <hip/hip_runtime.h>
#include <hip/hip_bf16.h>

// Problem constants (ClusterMemory forward, mode='CM')
#define NSAMP   65536
#define NFEAT   256
#define BATCHSZ 512
#define LOGITS_ELEMS ((size_t)BATCHSZ * NSAMP)

typedef __attribute__((ext_vector_type(4))) float f32x4;
typedef __attribute__((ext_vector_type(8))) short bf16x8;

// GEMM tiling
#define BM 128
#define BN 128
#define BK 64

// Packed-operand layout in d_ws (bf16 hi/lo, pre-tiled + XOR-swizzled so the
// GEMM can global_load_lds them linearly; each (panel,ks) chunk is a 16 KiB
// LDS image: byte = r*128 + ((slot*16) ^ ((r&7)<<4)) holding row r, k-slot).
#define B_HI_OFF ((size_t)0)
#define B_LO_OFF ((size_t)33554432)          // 32 MiB
#define A_HI_OFF ((size_t)67108864)          // 64 MiB
#define A_LO_OFF ((size_t)67371008)          // 64 MiB + 256 KiB
#define WS_NEEDED ((size_t)(67371008 + 262144))
#define CHUNK_BYTES 16384

#define FSLOTS (NSAMP * (NFEAT / 8))         // 2097152 8-elem slots (features)
#define ASLOTS (BATCHSZ * (NFEAT / 8))       // 16384 (inputs)

__device__ inline unsigned short bf16_bits(float x) {
  return __builtin_bit_cast(unsigned short, __float2bfloat16(x));
}

// async global->LDS DMA, 16B per lane. HW dest = readfirstlane(lp) + lane*16;
// our per-lane lp = base + tid*16 decomposes exactly that way per wave.
#define GLOAD_LDS16(gp, lp)                                         \
  __builtin_amdgcn_global_load_lds(                                 \
      (const __attribute__((address_space(1))) void*)(gp),          \
      (__attribute__((address_space(3))) void*)(lp), 16, 0, 0)

// ---------------------------------------------------------------------------
// Pack: fp32 -> bf16 hi/lo split, written as pre-swizzled LDS tile images.
// Also does the features -> new_features fp32 passthrough copy.
// ---------------------------------------------------------------------------
__global__ __launch_bounds__(256)
void cm_pack_kernel(const float* __restrict__ inputs,
                    const float* __restrict__ features,
                    char* __restrict__ ws,
                    float* __restrict__ newF) {
  const int idx = blockIdx.x * 256 + threadIdx.x;  // one 8-float slot/thread
  const float* g;
  size_t dst_hi, dst_lo;
  if (idx < FSLOTS) {
    const int R = idx >> 5, s5 = idx & 31;         // row, slot-of-32
    g = features + (size_t)R * NFEAT + s5 * 8;
    const int p = R >> 7, r = R & 127, ks = s5 >> 3, slot = s5 & 7;
    const size_t off = (size_t)(p * 4 + ks) * CHUNK_BYTES +
                       r * 128 + ((slot * 16) ^ ((r & 7) << 4));
    dst_hi = B_HI_OFF + off;
    dst_lo = B_LO_OFF + off;
    // passthrough copy into new_features output region
    float* o = newF + (size_t)R * NFEAT + s5 * 8;
    *(f32x4*)o       = *(const f32x4*)g;
    *(f32x4*)(o + 4) = *(const f32x4*)(g + 4);
  } else if (idx < FSLOTS + ASLOTS) {
    const int j = idx - FSLOTS;
    const int R = j >> 5, s5 = j & 31;
    g = inputs + (size_t)R * NFEAT + s5 * 8;
    const int p = R >> 7, r = R & 127, ks = s5 >> 3, slot = s5 & 7;
    const size_t off = (size_t)(p * 4 + ks) * CHUNK_BYTES +
                       r * 128 + ((slot * 16) ^ ((r & 7) << 4));
    dst_hi = A_HI_OFF + off;
    dst_lo = A_LO_OFF + off;
  } else {
    return;
  }
  f32x4 v0 = *(const f32x4*)g;
  f32x4 v1 = *(const f32x4*)(g + 4);
  bf16x8 hi, lo;
  #pragma unroll
  for (int e = 0; e < 8; ++e) {
    float x = (e < 4) ? v0[e & 3] : v1[e & 3];
    unsigned short h = bf16_bits(x);
    float hf = __bfloat162float(__builtin_bit_cast(__hip_bfloat16, h));
    hi[e] = (short)h;
    lo[e] = (short)bf16_bits(x - hf);
  }
  *(bf16x8*)(ws + dst_hi) = hi;
  *(bf16x8*)(ws + dst_lo) = lo;
}

// ---------------------------------------------------------------------------
// Shared MFMA inner body + epilogue (both GEMM variants use identical math).
// smem layout: Ahi | Alo | Bhi | Blo, 16 KiB each, XOR-swizzled rows.
// ---------------------------------------------------------------------------
__device__ __forceinline__ void mfma_block(const char* smem, int lane,
                                           int m_off, int n_off,
                                           f32x4 acc[4][4]) {
  #pragma unroll
  for (int kc = 0; kc < 2; ++kc) {
    const int kbyte = kc * 64 + ((lane >> 4) << 4);
    const int xr    = (lane & 7) << 4;  // == (row&7)<<4 for all frag rows
    bf16x8 ah[4], al[4], bh[4], bl[4];
    #pragma unroll
    for (int m = 0; m < 4; ++m) {
      const int r   = m_off + m * 16 + (lane & 15);
      const int off = r * 128 + (kbyte ^ xr);
      ah[m] = *(const bf16x8*)(smem + off);
      al[m] = *(const bf16x8*)(smem + CHUNK_BYTES + off);
    }
    #pragma unroll
    for (int n = 0; n < 4; ++n) {
      const int r   = n_off + n * 16 + (lane & 15);
      const int off = r * 128 + (kbyte ^ xr);
      bh[n] = *(const bf16x8*)(smem + 2 * CHUNK_BYTES + off);
      bl[n] = *(const bf16x8*)(smem + 3 * CHUNK_BYTES + off);
    }
    #pragma unroll
    for (int m = 0; m < 4; ++m)
      #pragma unroll
      for (int n = 0; n < 4; ++n) {
        acc[m][n] = __builtin_amdgcn_mfma_f32_16x16x32_bf16(ah[m], bh[n], acc[m][n], 0, 0, 0);
        acc[m][n] = __builtin_amdgcn_mfma_f32_16x16x32_bf16(al[m], bh[n], acc[m][n], 0, 0, 0);
        acc[m][n] = __builtin_amdgcn_mfma_f32_16x16x32_bf16(ah[m], bl[n], acc[m][n], 0, 0, 0);
      }
  }
}

__device__ __forceinline__ void gemm_epilogue(float* logits, f32x4 acc[4][4],
                                              int m_tile, int n_tile,
                                              int m_off, int n_off, int lane) {
  // C/D mapping col=lane&15, row=(lane>>4)*4+reg [m89]
  const float scale = 20.0f;  // 1/0.05
  const int c_col      = n_tile * BN + n_off + (lane & 15);
  const int c_row_base = m_tile * BM + m_off + ((lane >> 4) << 2);
  #pragma unroll
  for (int m = 0; m < 4; ++m) {
    #pragma unroll
    for (int n = 0; n < 4; ++n) {
      f32x4 v = acc[m][n];
      size_t base = (size_t)(c_row_base + m * 16) * NSAMP + (size_t)(c_col + n * 16);
      logits[base]             = v[0] * scale;
      logits[base + NSAMP]     = v[1] * scale;
      logits[base + 2 * NSAMP] = v[2] * scale;
      logits[base + 3 * NSAMP] = v[3] * scale;
    }
  }
}

// ---------------------------------------------------------------------------
// Fast GEMM: operands pre-packed in ws; stage via global_load_lds DMA.
// ---------------------------------------------------------------------------
__global__ __launch_bounds__(256, 2)
void cm_gemm_kernel(const char* __restrict__ ws,
                    float* __restrict__ logits) {
  __shared__ __align__(16) char smem[4 * CHUNK_BYTES];  // Ahi|Alo|Bhi|Blo

  const int tid = threadIdx.x;
  const int bid = blockIdx.x;
  // XCD-chunked bijective swizzle (nwg=2048, 2048%8==0): each XCD gets 256
  // consecutive swz ids -> the 4 m-tile sharers of a B-panel share one L2.
  const int swz    = (bid & 7) * 256 + (bid >> 3);
  const int m_tile = swz & 3;
  const int n_tile = swz >> 2;

  const int wave  = tid >> 6;
  const int lane  = tid & 63;
  const int m_off = (wave >> 1) * 64;
  const int n_off = (wave & 1) * 64;

  f32x4 acc[4][4];
  #pragma unroll
  for (int m = 0; m < 4; ++m)
    #pragma unroll
    for (int n = 0; n < 4; ++n) {
      acc[m][n][0] = 0.0f; acc[m][n][1] = 0.0f;
      acc[m][n][2] = 0.0f; acc[m][n][3] = 0.0f;
    }

  const size_t a_base = (size_t)(m_tile * 4) * CHUNK_BYTES;
  const size_t b_base = (size_t)(n_tile * 4) * CHUNK_BYTES;

  for (int ks = 0; ks < 4; ++ks) {
    if (ks) __syncthreads();  // all waves done reading LDS before DMA rewrite

    // ---- stage: 16x global_load_lds_dwordx4 (4 per 16KB chunk) ----
    const size_t ac = a_base + (size_t)ks * CHUNK_BYTES;
    const size_t bc = b_base + (size_t)ks * CHUNK_BYTES;
    #pragma unroll
    for (int i = 0; i < 4; ++i) {
      const size_t t = (size_t)i * 4096 + (size_t)tid * 16;
      GLOAD_LDS16(ws + A_HI_OFF + ac + t, smem + 0 * CHUNK_BYTES + t);
      GLOAD_LDS16(ws + A_LO_OFF + ac + t, smem + 1 * CHUNK_BYTES + t);
      GLOAD_LDS16(ws + B_HI_OFF + bc + t, smem + 2 * CHUNK_BYTES + t);
      GLOAD_LDS16(ws + B_LO_OFF + bc + t, smem + 3 * CHUNK_BYTES + t);
    }
    __syncthreads();  // drains vmcnt -> DMA'd tiles visible

    mfma_block(smem, lane, m_off, n_off, acc);
  }

  gemm_epilogue(logits, acc, m_tile, n_tile, m_off, n_off, lane);
}

// ---------------------------------------------------------------------------
// Fallback GEMM (round-3, PASSED at 310us): reg-staged conversion, fused
// features->newF copy. Used only if ws_size is too small for packing.
// ---------------------------------------------------------------------------
__global__ __launch_bounds__(256, 2)
void cm_gemm_fused_kernel(const float* __restrict__ inputs,
                          const float* __restrict__ features,
                          float* __restrict__ logits,
                          float* __restrict__ newF) {
  __shared__ __align__(16) char smem[4 * CHUNK_BYTES];

  const int tid    = threadIdx.x;
  const int bidx   = blockIdx.x;
  const int m_tile = bidx & 3;
  const int n_tile = bidx >> 2;
  const int bm0    = m_tile * BM;
  const int bn0    = n_tile * BN;

  const int wave  = tid >> 6;
  const int lane  = tid & 63;
  const int m_off = (wave >> 1) * 64;
  const int n_off = (wave & 1) * 64;

  f32x4 acc[4][4];
  #pragma unroll
  for (int m = 0; m < 4; ++m)
    #pragma unroll
    for (int n = 0; n < 4; ++n) {
      acc[m][n][0] = 0.0f; acc[m][n][1] = 0.0f;
      acc[m][n][2] = 0.0f; acc[m][n][3] = 0.0f;
    }

  const int srow = tid >> 3;
  const int slot = tid & 7;

  for (int ks = 0; ks < 4; ++ks) {
    const int k0 = ks * BK;
    if (ks) __syncthreads();

    #pragma unroll
    for (int s = 0; s < 4; ++s) {
      const int row     = srow + s * 32;
      const int byteoff = row * 128 + ((slot * 16) ^ ((row & 7) << 4));
      {
        const float* g = inputs + (size_t)(bm0 + row) * NFEAT + k0 + slot * 8;
        f32x4 v0 = *(const f32x4*)g;
        f32x4 v1 = *(const f32x4*)(g + 4);
        bf16x8 hi, lo;
        #pragma unroll
        for (int e = 0; e < 8; ++e) {
          float x = (e < 4) ? v0[e & 3] : v1[e & 3];
          unsigned short h = bf16_bits(x);
          float hf = __bfloat162float(__builtin_bit_cast(__hip_bfloat16, h));
          hi[e] = (short)h;
          lo[e] = (short)bf16_bits(x - hf);
        }
        *(bf16x8*)(smem + byteoff)               = hi;
        *(bf16x8*)(smem + CHUNK_BYTES + byteoff) = lo;
      }
      {
        const float* g = features + (size_t)(bn0 + row) * NFEAT + k0 + slot * 8;
        f32x4 v0 = *(const f32x4*)g;
        f32x4 v1 = *(const f32x4*)(g + 4);
        bf16x8 hi, lo;
        #pragma unroll
        for (int e = 0; e < 8; ++e) {
          float x = (e < 4) ? v0[e & 3] : v1[e & 3];
          unsigned short h = bf16_bits(x);
          float hf = __bfloat162float(__builtin_bit_cast(__hip_bfloat16, h));
          hi[e] = (short)h;
          lo[e] = (short)bf16_bits(x - hf);
        }
        *(bf16x8*)(smem + 2 * CHUNK_BYTES + byteoff) = hi;
        *(bf16x8*)(smem + 3 * CHUNK_BYTES + byteoff) = lo;
        if (m_tile == 0) {
          float* o = newF + (size_t)(bn0 + row) * NFEAT + k0 + slot * 8;
          *(f32x4*)o       = v0;
          *(f32x4*)(o + 4) = v1;
        }
      }
    }
    __syncthreads();

    mfma_block(smem, lane, m_off, n_off, acc);
  }

  gemm_epilogue(logits, acc, m_tile, n_tile, m_off, n_off, lane);
}

// ---------------------------------------------------------------------------
// Order-dependent EMA scatter: one wave per batch index. Only the LAST batch
// index targeting a given row writes; it replays the full ordered chain.
// ---------------------------------------------------------------------------
__global__ __launch_bounds__(64)
void cm_update_kernel(const float* __restrict__ inputs,
                      const int* __restrict__ targets,
                      const float* __restrict__ features,
                      float* __restrict__ newF) {
  const int i    = blockIdx.x;
  const int lane = threadIdx.x;
  const int y    = targets[i];

  unsigned long long m[8];
  #pragma unroll
  for (int c = 0; c < 8; ++c)
    m[c] = __ballot(targets[c * 64 + lane] == y);

  int maxj = -1;
  #pragma unroll
  for (int c = 7; c >= 0; --c)
    if (maxj < 0 && m[c]) maxj = c * 64 + 63 - __clzll(m[c]);
  if (maxj != i) return;  // not the last writer for y

  f32x4 row = *(const f32x4*)(features + (size_t)y * NFEAT + lane * 4);
  for (int c = 0; c < 8; ++c) {
    unsigned long long mm = m[c];
    while (mm) {  // wave-uniform loop (ballot masks are uniform)
      const int b = __builtin_ctzll(mm);
      mm &= mm - 1;
      const int j = c * 64 + b;
      f32x4 x = *(const f32x4*)(inputs + (size_t)j * NFEAT + lane * 4);
      row[0] = 0.2f * row[0] + 0.8f * x[0];
      row[1] = 0.2f * row[1] + 0.8f * x[1];
      row[2] = 0.2f * row[2] + 0.8f * x[2];
      row[3] = 0.2f * row[3] + 0.8f * x[3];
      float p = row[0]*row[0] + row[1]*row[1] + row[2]*row[2] + row[3]*row[3];
      #pragma unroll
      for (int off = 32; off >= 1; off >>= 1)
        p += __shfl_xor(p, off);
      const float inv = 1.0f / sqrtf(p + 1e-12f);
      row[0] *= inv; row[1] *= inv; row[2] *= inv; row[3] *= inv;
    }
  }
  *(f32x4*)(newF + (size_t)y * NFEAT + lane * 4) = row;
}

// ---------------------------------------------------------------------------
extern "C" void kernel_launch(void* const* d_in, const int* in_sizes, int n_in,
                              void* d_out, int out_size, void* d_ws, size_t ws_size,
                              hipStream_t stream) {
  const float* inputs   = (const float*)d_in[0];
  const int*   targets  = (const int*)d_in[1];
  const float* features = (const float*)d_in[2];
  float* logits = (float*)d_out;
  float* newF   = (float*)d_out + LOGITS_ELEMS;

  const int grid = (NSAMP / BN) * (BATCHSZ / BM);  // 2048

  if (ws_size >= WS_NEEDED) {
    char* ws = (char*)d_ws;
    const int pack_blocks = (FSLOTS + ASLOTS) / 256;  // 8256
    cm_pack_kernel<<<pack_blocks, 256, 0, stream>>>(inputs, features, ws, newF);
    cm_gemm_kernel<<<grid, 256, 0, stream>>>(ws, logits);
  } else {
    // workspace too small for packing: round-3 fused path (verified pass)
    cm_gemm_fused_kernel<<<grid, 256, 0, stream>>>(inputs, features, logits, newF);
  }

  cm_update_kernel<<<BATCHSZ, 64, 0, stream>>>(inputs, targets, features, newF);
}

// Round 12
// 310.846 us; speedup vs baseline: 1.0044x; 1.0044x over previous
//
#include <hip/hip_runtime.h>
#include <hip/hip_bf16.h>

// Problem constants (ClusterMemory forward, mode='CM')
#define NSAMP   65536
#define NFEAT   256
#define BATCHSZ 512
#define LOGITS_ELEMS ((size_t)BATCHSZ * NSAMP)

typedef __attribute__((ext_vector_type(4))) float f32x4;
typedef __attribute__((ext_vector_type(8))) short bf16x8;

// GEMM tiling: 128x128 tile, K chunked in 8 steps of BK=32 (double-buffered)
#define BM 128
#define BN 128

// Packed-operand layout in d_ws. Each (panel, s) chunk is an 8 KiB LDS image:
// byte = r*64 + ((sl*16) ^ ((r&3)<<4)); r = row-in-panel, sl = 8-elem k-slot
// within the 32-k chunk. B: 512 panels x 8 chunks; A: 4 panels x 8 chunks.
#define CHUNK 8192
#define B_HI_OFF ((size_t)0)
#define B_LO_OFF ((size_t)33554432)          // 32 MiB
#define A_HI_OFF ((size_t)67108864)          // 64 MiB
#define A_LO_OFF ((size_t)67371008)          // 64 MiB + 256 KiB
#define WS_NEEDED ((size_t)(67371008 + 262144))
#define OLDCHUNK 16384                        // fallback kernel's LDS plane

#define FSLOTS (NSAMP * (NFEAT / 8))         // 2097152 8-elem slots (features)
#define ASLOTS (BATCHSZ * (NFEAT / 8))       // 16384 (inputs)

__device__ inline unsigned short bf16_bits(float x) {
  return __builtin_bit_cast(unsigned short, __float2bfloat16(x));
}

// async global->LDS DMA, 16B per lane. HW dest = readfirstlane(lp) + lane*16;
// our per-lane lp = base + tid*16 decomposes exactly that way per wave.
#define GLOAD_LDS16(gp, lp)                                         \
  __builtin_amdgcn_global_load_lds(                                 \
      (const __attribute__((address_space(1))) void*)(gp),          \
      (__attribute__((address_space(3))) void*)(lp), 16, 0, 0)

// ---------------------------------------------------------------------------
// Pack: fp32 -> bf16 hi/lo split, written as pre-swizzled 8KB LDS chunk
// images (BK=32). Also does the features -> new_features passthrough copy.
// ---------------------------------------------------------------------------
__global__ __launch_bounds__(256)
void cm_pack_kernel(const float* __restrict__ inputs,
                    const float* __restrict__ features,
                    char* __restrict__ ws,
                    float* __restrict__ newF) {
  const int idx = blockIdx.x * 256 + threadIdx.x;  // one 8-float slot/thread
  const float* g;
  size_t dst_hi, dst_lo;
  if (idx < FSLOTS) {
    const int R = idx >> 5, s5 = idx & 31;         // row, 8-elem k-group
    g = features + (size_t)R * NFEAT + s5 * 8;
    const int p = R >> 7, r = R & 127, s = s5 >> 2, sl = s5 & 3;
    const size_t off = (size_t)(p * 8 + s) * CHUNK +
                       r * 64 + ((sl * 16) ^ ((r & 3) << 4));
    dst_hi = B_HI_OFF + off;
    dst_lo = B_LO_OFF + off;
    // passthrough copy into new_features output region
    float* o = newF + (size_t)R * NFEAT + s5 * 8;
    *(f32x4*)o       = *(const f32x4*)g;
    *(f32x4*)(o + 4) = *(const f32x4*)(g + 4);
  } else if (idx < FSLOTS + ASLOTS) {
    const int j = idx - FSLOTS;
    const int R = j >> 5, s5 = j & 31;
    g = inputs + (size_t)R * NFEAT + s5 * 8;
    const int p = R >> 7, r = R & 127, s = s5 >> 2, sl = s5 & 3;
    const size_t off = (size_t)(p * 8 + s) * CHUNK +
                       r * 64 + ((sl * 16) ^ ((r & 3) << 4));
    dst_hi = A_HI_OFF + off;
    dst_lo = A_LO_OFF + off;
  } else {
    return;
  }
  f32x4 v0 = *(const f32x4*)g;
  f32x4 v1 = *(const f32x4*)(g + 4);
  bf16x8 hi, lo;
  #pragma unroll
  for (int e = 0; e < 8; ++e) {
    float x = (e < 4) ? v0[e & 3] : v1[e & 3];
    unsigned short h = bf16_bits(x);
    float hf = __bfloat162float(__builtin_bit_cast(__hip_bfloat16, h));
    hi[e] = (short)h;
    lo[e] = (short)bf16_bits(x - hf);
  }
  *(bf16x8*)(ws + dst_hi) = hi;
  *(bf16x8*)(ws + dst_lo) = lo;
}

__device__ __forceinline__ void gemm_epilogue(float* logits, f32x4 acc[4][4],
                                              int m_tile, int n_tile,
                                              int m_off, int n_off, int lane) {
  // C/D mapping col=lane&15, row=(lane>>4)*4+reg [m89]
  const float scale = 20.0f;  // 1/0.05
  const int c_col      = n_tile * BN + n_off + (lane & 15);
  const int c_row_base = m_tile * BM + m_off + ((lane >> 4) << 2);
  #pragma unroll
  for (int m = 0; m < 4; ++m) {
    #pragma unroll
    for (int n = 0; n < 4; ++n) {
      f32x4 v = acc[m][n];
      size_t base = (size_t)(c_row_base + m * 16) * NSAMP + (size_t)(c_col + n * 16);
      logits[base]             = v[0] * scale;
      logits[base + NSAMP]     = v[1] * scale;
      logits[base + 2 * NSAMP] = v[2] * scale;
      logits[base + 3 * NSAMP] = v[3] * scale;
    }
  }
}

// ---------------------------------------------------------------------------
// Fast GEMM: 8-step K-loop (BK=32), double-buffered LDS, 2-phase prefetch:
// issue step s+1's DMA before computing step s; one barrier per step.
// ---------------------------------------------------------------------------
__global__ __launch_bounds__(256, 2)
void cm_gemm_kernel(const char* __restrict__ ws,
                    float* __restrict__ logits) {
  // [buf][Ahi|Alo|Bhi|Blo], 8 KiB each -> 64 KiB total (2 blocks/CU)
  __shared__ __align__(16) char smem[2][4 * CHUNK];

  const int tid = threadIdx.x;
  const int bid = blockIdx.x;
  // XCD-chunked bijective swizzle (nwg=2048 % 8 == 0): each XCD gets 256
  // consecutive swz ids -> the 4 m-tile sharers of a B-panel share one L2.
  const int swz    = (bid & 7) * 256 + (bid >> 3);
  const int m_tile = swz & 3;
  const int n_tile = swz >> 2;

  const int wave  = tid >> 6;
  const int lane  = tid & 63;
  const int m_off = (wave >> 1) * 64;
  const int n_off = (wave & 1) * 64;

  f32x4 acc[4][4];
  #pragma unroll
  for (int m = 0; m < 4; ++m)
    #pragma unroll
    for (int n = 0; n < 4; ++n) {
      acc[m][n][0] = 0.0f; acc[m][n][1] = 0.0f;
      acc[m][n][2] = 0.0f; acc[m][n][3] = 0.0f;
    }

  const size_t a_base = (size_t)(m_tile * 8) * CHUNK;
  const size_t b_base = (size_t)(n_tile * 8) * CHUNK;

  // stage chunk s into buffer buf: 8x global_load_lds_dwordx4
  #define STAGE(buf, s)                                                     \
    do {                                                                    \
      const size_t ac = a_base + (size_t)(s) * CHUNK;                       \
      const size_t bc = b_base + (size_t)(s) * CHUNK;                       \
      _Pragma("unroll")                                                     \
      for (int i = 0; i < 2; ++i) {                                         \
        const size_t t = (size_t)i * 4096 + (size_t)tid * 16;               \
        GLOAD_LDS16(ws + A_HI_OFF + ac + t, &smem[buf][0 * CHUNK + t]);     \
        GLOAD_LDS16(ws + A_LO_OFF + ac + t, &smem[buf][1 * CHUNK + t]);     \
        GLOAD_LDS16(ws + B_HI_OFF + bc + t, &smem[buf][2 * CHUNK + t]);     \
        GLOAD_LDS16(ws + B_LO_OFF + bc + t, &smem[buf][3 * CHUNK + t]);     \
      }                                                                     \
    } while (0)

  STAGE(0, 0);
  __syncthreads();  // vmcnt(0) drain: buffer 0 ready

  #pragma unroll
  for (int s = 0; s < 8; ++s) {
    if (s < 7) STAGE((s + 1) & 1, s + 1);  // prefetch next chunk

    // ---- compute chunk s from buf s&1: 16 ds_read_b128 + 48 MFMA ----
    {
      const char* sm  = smem[s & 1];
      const int kbyte = (lane >> 4) << 4;  // k-slot per MFMA A/B layout
      bf16x8 ah[4], al[4], bh[4], bl[4];
      #pragma unroll
      for (int m = 0; m < 4; ++m) {
        const int r   = m_off + m * 16 + (lane & 15);
        const int off = r * 64 + (kbyte ^ ((r & 3) << 4));
        ah[m] = *(const bf16x8*)(sm + off);
        al[m] = *(const bf16x8*)(sm + CHUNK + off);
      }
      #pragma unroll
      for (int n = 0; n < 4; ++n) {
        const int r   = n_off + n * 16 + (lane & 15);
        const int off = r * 64 + (kbyte ^ ((r & 3) << 4));
        bh[n] = *(const bf16x8*)(sm + 2 * CHUNK + off);
        bl[n] = *(const bf16x8*)(sm + 3 * CHUNK + off);
      }
      #pragma unroll
      for (int m = 0; m < 4; ++m)
        #pragma unroll
        for (int n = 0; n < 4; ++n) {
          acc[m][n] = __builtin_amdgcn_mfma_f32_16x16x32_bf16(ah[m], bh[n], acc[m][n], 0, 0, 0);
          acc[m][n] = __builtin_amdgcn_mfma_f32_16x16x32_bf16(al[m], bh[n], acc[m][n], 0, 0, 0);
          acc[m][n] = __builtin_amdgcn_mfma_f32_16x16x32_bf16(ah[m], bl[n], acc[m][n], 0, 0, 0);
        }
    }

    __syncthreads();  // drains vmcnt (next buffer ready) + LDS-read fence
  }
  #undef STAGE

  gemm_epilogue(logits, acc, m_tile, n_tile, m_off, n_off, lane);
}

// ---------------------------------------------------------------------------
// Fallback GEMM (round-3 structure, PASSED at 310us): reg-staged conversion,
// BK=64, fused features->newF copy. Used only if ws_size is too small.
// ---------------------------------------------------------------------------
__global__ __launch_bounds__(256, 2)
void cm_gemm_fused_kernel(const float* __restrict__ inputs,
                          const float* __restrict__ features,
                          float* __restrict__ logits,
                          float* __restrict__ newF) {
  __shared__ __align__(16) char smem[4 * OLDCHUNK];

  const int tid    = threadIdx.x;
  const int bidx   = blockIdx.x;
  const int m_tile = bidx & 3;
  const int n_tile = bidx >> 2;
  const int bm0    = m_tile * BM;
  const int bn0    = n_tile * BN;

  const int wave  = tid >> 6;
  const int lane  = tid & 63;
  const int m_off = (wave >> 1) * 64;
  const int n_off = (wave & 1) * 64;

  f32x4 acc[4][4];
  #pragma unroll
  for (int m = 0; m < 4; ++m)
    #pragma unroll
    for (int n = 0; n < 4; ++n) {
      acc[m][n][0] = 0.0f; acc[m][n][1] = 0.0f;
      acc[m][n][2] = 0.0f; acc[m][n][3] = 0.0f;
    }

  const int srow = tid >> 3;
  const int slot = tid & 7;

  for (int ks = 0; ks < 4; ++ks) {
    const int k0 = ks * 64;
    if (ks) __syncthreads();

    #pragma unroll
    for (int s = 0; s < 4; ++s) {
      const int row     = srow + s * 32;
      const int byteoff = row * 128 + ((slot * 16) ^ ((row & 7) << 4));
      {
        const float* g = inputs + (size_t)(bm0 + row) * NFEAT + k0 + slot * 8;
        f32x4 v0 = *(const f32x4*)g;
        f32x4 v1 = *(const f32x4*)(g + 4);
        bf16x8 hi, lo;
        #pragma unroll
        for (int e = 0; e < 8; ++e) {
          float x = (e < 4) ? v0[e & 3] : v1[e & 3];
          unsigned short h = bf16_bits(x);
          float hf = __bfloat162float(__builtin_bit_cast(__hip_bfloat16, h));
          hi[e] = (short)h;
          lo[e] = (short)bf16_bits(x - hf);
        }
        *(bf16x8*)(smem + byteoff)            = hi;
        *(bf16x8*)(smem + OLDCHUNK + byteoff) = lo;
      }
      {
        const float* g = features + (size_t)(bn0 + row) * NFEAT + k0 + slot * 8;
        f32x4 v0 = *(const f32x4*)g;
        f32x4 v1 = *(const f32x4*)(g + 4);
        bf16x8 hi, lo;
        #pragma unroll
        for (int e = 0; e < 8; ++e) {
          float x = (e < 4) ? v0[e & 3] : v1[e & 3];
          unsigned short h = bf16_bits(x);
          float hf = __bfloat162float(__builtin_bit_cast(__hip_bfloat16, h));
          hi[e] = (short)h;
          lo[e] = (short)bf16_bits(x - hf);
        }
        *(bf16x8*)(smem + 2 * OLDCHUNK + byteoff) = hi;
        *(bf16x8*)(smem + 3 * OLDCHUNK + byteoff) = lo;
        if (m_tile == 0) {
          float* o = newF + (size_t)(bn0 + row) * NFEAT + k0 + slot * 8;
          *(f32x4*)o       = v0;
          *(f32x4*)(o + 4) = v1;
        }
      }
    }
    __syncthreads();

    #pragma unroll
    for (int kc = 0; kc < 2; ++kc) {
      const int kbyte = kc * 64 + ((lane >> 4) << 4);
      const int xr    = (lane & 7) << 4;
      bf16x8 ah[4], al[4], bh[4], bl[4];
      #pragma unroll
      for (int m = 0; m < 4; ++m) {
        const int r   = m_off + m * 16 + (lane & 15);
        const int off = r * 128 + (kbyte ^ xr);
        ah[m] = *(const bf16x8*)(smem + off);
        al[m] = *(const bf16x8*)(smem + OLDCHUNK + off);
      }
      #pragma unroll
      for (int n = 0; n < 4; ++n) {
        const int r   = n_off + n * 16 + (lane & 15);
        const int off = r * 128 + (kbyte ^ xr);
        bh[n] = *(const bf16x8*)(smem + 2 * OLDCHUNK + off);
        bl[n] = *(const bf16x8*)(smem + 3 * OLDCHUNK + off);
      }
      #pragma unroll
      for (int m = 0; m < 4; ++m)
        #pragma unroll
        for (int n = 0; n < 4; ++n) {
          acc[m][n] = __builtin_amdgcn_mfma_f32_16x16x32_bf16(ah[m], bh[n], acc[m][n], 0, 0, 0);
          acc[m][n] = __builtin_amdgcn_mfma_f32_16x16x32_bf16(al[m], bh[n], acc[m][n], 0, 0, 0);
          acc[m][n] = __builtin_amdgcn_mfma_f32_16x16x32_bf16(ah[m], bl[n], acc[m][n], 0, 0, 0);
        }
    }
  }

  gemm_epilogue(logits, acc, m_tile, n_tile, m_off, n_off, lane);
}

// ---------------------------------------------------------------------------
// Order-dependent EMA scatter: one wave per batch index. Only the LAST batch
// index targeting a given row writes; it replays the full ordered chain.
// ---------------------------------------------------------------------------
__global__ __launch_bounds__(64)
void cm_update_kernel(const float* __restrict__ inputs,
                      const int* __restrict__ targets,
                      const float* __restrict__ features,
                      float* __restrict__ newF) {
  const int i    = blockIdx.x;
  const int lane = threadIdx.x;
  const int y    = targets[i];

  unsigned long long m[8];
  #pragma unroll
  for (int c = 0; c < 8; ++c)
    m[c] = __ballot(targets[c * 64 + lane] == y);

  int maxj = -1;
  #pragma unroll
  for (int c = 7; c >= 0; --c)
    if (maxj < 0 && m[c]) maxj = c * 64 + 63 - __clzll(m[c]);
  if (maxj != i) return;  // not the last writer for y

  f32x4 row = *(const f32x4*)(features + (size_t)y * NFEAT + lane * 4);
  for (int c = 0; c < 8; ++c) {
    unsigned long long mm = m[c];
    while (mm) {  // wave-uniform loop (ballot masks are uniform)
      const int b = __builtin_ctzll(mm);
      mm &= mm - 1;
      const int j = c * 64 + b;
      f32x4 x = *(const f32x4*)(inputs + (size_t)j * NFEAT + lane * 4);
      row[0] = 0.2f * row[0] + 0.8f * x[0];
      row[1] = 0.2f * row[1] + 0.8f * x[1];
      row[2] = 0.2f * row[2] + 0.8f * x[2];
      row[3] = 0.2f * row[3] + 0.8f * x[3];
      float p = row[0]*row[0] + row[1]*row[1] + row[2]*row[2] + row[3]*row[3];
      #pragma unroll
      for (int off = 32; off >= 1; off >>= 1)
        p += __shfl_xor(p, off);
      const float inv = 1.0f / sqrtf(p + 1e-12f);
      row[0] *= inv; row[1] *= inv; row[2] *= inv; row[3] *= inv;
    }
  }
  *(f32x4*)(newF + (size_t)y * NFEAT + lane * 4) = row;
}

// ---------------------------------------------------------------------------
extern "C" void kernel_launch(void* const* d_in, const int* in_sizes, int n_in,
                              void* d_out, int out_size, void* d_ws, size_t ws_size,
                              hipStream_t stream) {
  const float* inputs   = (const float*)d_in[0];
  const int*   targets  = (const int*)d_in[1];
  const float* features = (const float*)d_in[2];
  float* logits = (float*)d_out;
  float* newF   = (float*)d_out + LOGITS_ELEMS;

  const int grid = (NSAMP / BN) * (BATCHSZ / BM);  // 2048

  if (ws_size >= WS_NEEDED) {
    char* ws = (char*)d_ws;
    const int pack_blocks = (FSLOTS + ASLOTS) / 256;  // 8256
    cm_pack_kernel<<<pack_blocks, 256, 0, stream>>>(inputs, features, ws, newF);
    cm_gemm_kernel<<<grid, 256, 0, stream>>>(ws, logits);
  } else {
    // workspace too small for packing: round-3 fused path (verified pass)
    cm_gemm_fused_kernel<<<grid, 256, 0, stream>>>(inputs, features, logits, newF);
  }

  cm_update_kernel<<<BATCHSZ, 64, 0, stream>>>(inputs, targets, features, newF);
}